// Round 1
// baseline (317.480 us; speedup 1.0000x reference)
//
#include <hip/hip_runtime.h>
#include <hip/hip_bf16.h>

// Problem constants (reference: B=2, H=16, S=2048, D=64, fp32 in/out)
#define B_ 2
#define H_ 16
#define S_ 2048
#define D_ 64
#define SCALE 0.125f   // 1/sqrt(64)

#define BK 32          // k-chunk per iteration
#define WQ 16          // q rows per wave

// LDS row strides (in bf16 elements). Chosen so b128 reads are 16B-aligned
// and give uniform 2-way bank access (free per m136).
#define KS_STRIDE 72   // 144B rows: bank base = 4*kcol -> 2-way
#define VS_STRIDE 40   // 80B rows:  bank base = 20*n   -> 2-way
#define PS_STRIDE 40   // 80B rows

typedef __attribute__((ext_vector_type(8))) short short8;
typedef __attribute__((ext_vector_type(4))) short short4v;
typedef __attribute__((ext_vector_type(4))) float float4v;

// fp32 -> bf16 bits with round-to-nearest-even
__device__ __forceinline__ short bf16bits(float x) {
    union { float f; unsigned u; } c; c.f = x;
    unsigned r = (c.u + 0x7FFFu + ((c.u >> 16) & 1u)) >> 16;
    return (short)r;
}

__global__ __launch_bounds__(256, 2)
void attn_flash_kernel(const float* __restrict__ Q, const float* __restrict__ K,
                       const float* __restrict__ V, const int* __restrict__ mask,
                       float* __restrict__ out)
{
    __shared__ short Ks[BK * KS_STRIDE];        // [k][d]  32 x 72
    __shared__ short Vs[D_ * VS_STRIDE];        // [d][k]  64 x 40 (transposed)
    __shared__ short Ps[4 * WQ * PS_STRIDE];    // per-wave 16 x 40

    const int tid  = threadIdx.x;
    const int lane = tid & 63;
    const int wave = tid >> 6;
    const int bh   = blockIdx.y;                // b*H + h
    const int b    = bh / H_;
    const int qbase = blockIdx.x * 64 + wave * WQ;

    const int l15  = lane & 15;
    const int quad = lane >> 4;

    const size_t qkv_base = (size_t)bh * S_ * D_;

    // ---- preload Q A-fragments (A[m=lane&15][k=quad*8+j]), fp32->bf16 ----
    short8 qf[2];
    {
        const float* qrow = Q + qkv_base + (size_t)(qbase + l15) * D_;
        for (int dc = 0; dc < 2; ++dc) {
            const int dstart = dc * 32 + quad * 8;
            short8 f;
            #pragma unroll
            for (int j = 0; j < 8; ++j) f[j] = bf16bits(qrow[dstart + j]);
            qf[dc] = f;
        }
    }

    // online-softmax state (per lane: rows quad*4 + r)
    float m_run[4], l_run[4];
    float4v o_acc[4];
    #pragma unroll
    for (int r = 0; r < 4; ++r) { m_run[r] = -INFINITY; l_run[r] = 0.0f; }
    #pragma unroll
    for (int nb = 0; nb < 4; ++nb) o_acc[nb] = (float4v){0.f, 0.f, 0.f, 0.f};

    const float* Kg0 = K + qkv_base;
    const float* Vg0 = V + qkv_base;
    const size_t mask_base = (size_t)b * S_ * S_;

    for (int kt = 0; kt < S_ / BK; ++kt) {
        __syncthreads();   // protect previous iteration's Ks/Vs reads

        // ---- cooperative staging: K chunk (row-major), V chunk (transposed) ----
        {
            const float* Kg = Kg0 + (size_t)kt * BK * D_;
            const float* Vg = Vg0 + (size_t)kt * BK * D_;
            #pragma unroll
            for (int i = 0; i < 2; ++i) {
                const int flat4 = tid + i * 256;     // 512 float4s = 32x64 elems
                const int k = flat4 >> 4;            // 16 float4 per row
                const int d = (flat4 & 15) * 4;
                float4 kv = *(const float4*)(Kg + k * D_ + d);
                short4v ks4;
                ks4[0] = bf16bits(kv.x); ks4[1] = bf16bits(kv.y);
                ks4[2] = bf16bits(kv.z); ks4[3] = bf16bits(kv.w);
                *(short4v*)&Ks[k * KS_STRIDE + d] = ks4;   // 8B aligned
                float4 vv = *(const float4*)(Vg + k * D_ + d);
                Vs[(d + 0) * VS_STRIDE + k] = bf16bits(vv.x);
                Vs[(d + 1) * VS_STRIDE + k] = bf16bits(vv.y);
                Vs[(d + 2) * VS_STRIDE + k] = bf16bits(vv.z);
                Vs[(d + 3) * VS_STRIDE + k] = bf16bits(vv.w);
            }
        }
        __syncthreads();

        // ---- S = Q @ K^T  (two 16x16 C-frags: nh = k-col halves) ----
        float4v s[2];
        #pragma unroll
        for (int nh = 0; nh < 2; ++nh) {
            float4v acc = (float4v){0.f, 0.f, 0.f, 0.f};
            #pragma unroll
            for (int dc = 0; dc < 2; ++dc) {
                const short8 bfrag =
                    *(const short8*)&Ks[(nh * 16 + l15) * KS_STRIDE + dc * 32 + quad * 8];
                acc = __builtin_amdgcn_mfma_f32_16x16x32_bf16(qf[dc], bfrag, acc, 0, 0, 0);
            }
            s[nh] = acc;
        }

        // ---- mask + scale (C layout: col = lane&15, row = quad*4 + r) ----
        const int kgbase = kt * BK;
        #pragma unroll
        for (int nh = 0; nh < 2; ++nh) {
            const int gcol = kgbase + nh * 16 + l15;
            #pragma unroll
            for (int r = 0; r < 4; ++r) {
                const int grow = qbase + quad * 4 + r;
                const int mv = mask[mask_base + (size_t)grow * S_ + gcol];
                s[nh][r] = mv ? -1e9f : s[nh][r] * SCALE;
            }
        }

        // ---- row max over the 16 lanes of this quad ----
        float alpha[4];
        #pragma unroll
        for (int r = 0; r < 4; ++r) {
            float t = fmaxf(s[0][r], s[1][r]);
            #pragma unroll
            for (int off = 1; off < 16; off <<= 1) t = fmaxf(t, __shfl_xor(t, off, 64));
            const float mnew = fmaxf(m_run[r], t);
            alpha[r] = __expf(m_run[r] - mnew);   // -inf -> 0 on first chunk
            m_run[r] = mnew;
        }

        // ---- p = exp(s - m), row sum, l update ----
        #pragma unroll
        for (int nh = 0; nh < 2; ++nh)
            #pragma unroll
            for (int r = 0; r < 4; ++r) s[nh][r] = __expf(s[nh][r] - m_run[r]);
        #pragma unroll
        for (int r = 0; r < 4; ++r) {
            float t = s[0][r] + s[1][r];
            #pragma unroll
            for (int off = 1; off < 16; off <<= 1) t += __shfl_xor(t, off, 64);
            l_run[r] = l_run[r] * alpha[r] + t;
        }

        // ---- rescale O ----
        #pragma unroll
        for (int nb = 0; nb < 4; ++nb)
            #pragma unroll
            for (int r = 0; r < 4; ++r) o_acc[nb][r] *= alpha[r];

        // ---- P: C layout -> LDS -> A layout (per-wave private region) ----
        short* pw = &Ps[wave * WQ * PS_STRIDE];
        #pragma unroll
        for (int nh = 0; nh < 2; ++nh)
            #pragma unroll
            for (int r = 0; r < 4; ++r)
                pw[(quad * 4 + r) * PS_STRIDE + nh * 16 + l15] = bf16bits(s[nh][r]);
        __syncthreads();   // wave-internal LDS visibility (cheap, uniform)

        const short8 pfrag = *(const short8*)&pw[l15 * PS_STRIDE + quad * 8];

        // ---- O += P @ V  (B-frag: B[k=quad*8+j][n=lane&15] from Vs[d][k]) ----
        #pragma unroll
        for (int nb = 0; nb < 4; ++nb) {
            const short8 vfrag =
                *(const short8*)&Vs[(nb * 16 + l15) * VS_STRIDE + quad * 8];
            o_acc[nb] = __builtin_amdgcn_mfma_f32_16x16x32_bf16(pfrag, vfrag, o_acc[nb], 0, 0, 0);
        }
    }

    // ---- epilogue: out = O / l ----
    #pragma unroll
    for (int nb = 0; nb < 4; ++nb) {
        #pragma unroll
        for (int r = 0; r < 4; ++r) {
            const int row = qbase + quad * 4 + r;
            const int col = nb * 16 + l15;
            out[qkv_base + (size_t)row * D_ + col] = o_acc[nb][r] / l_run[r];
        }
    }
}

extern "C" void kernel_launch(void* const* d_in, const int* in_sizes, int n_in,
                              void* d_out, int out_size, void* d_ws, size_t ws_size,
                              hipStream_t stream) {
    const float* Q    = (const float*)d_in[0];
    const float* K    = (const float*)d_in[1];
    const float* V    = (const float*)d_in[2];
    const int*   mask = (const int*)d_in[3];
    float* out = (float*)d_out;

    dim3 grid(S_ / 64, B_ * H_);   // 32 x 32 blocks
    dim3 block(256);
    attn_flash_kernel<<<grid, block, 0, stream>>>(Q, K, V, mask, out);
}

// Round 3
// 233.710 us; speedup vs baseline: 1.3584x; 1.3584x over previous
//
#include <hip/hip_runtime.h>

// Problem: B=2, H=16, S=2048, D=64, fp32 in/out, int mask (nonzero = masked)
#define B_ 2
#define H_ 16
#define S_ 2048
#define D_ 64
#define BK 32
#define NKT (S_ / BK)          // 64 k-chunks
// scale folded into Q, in exp2 space: (1/sqrt(64)) * log2(e)
#define QSCALE 0.18033688011112042f

// LDS strides (dwords)
#define KSD 36                 // K row: 64 f16 = 32 dw + 4 pad
#define VTD 18                 // Vt row: 16 k-pairs + 2 pad
#define KS_SZ (BK * KSD)       // 1152 dw per buffer
#define VT_SZ (D_ * VTD)       // 1152 dw per buffer

typedef __attribute__((ext_vector_type(4))) float  float4v;
typedef __attribute__((ext_vector_type(2))) _Float16 half2v;
typedef __attribute__((ext_vector_type(4))) _Float16 half4v;
typedef __attribute__((ext_vector_type(8))) _Float16 half8v;
typedef __attribute__((ext_vector_type(2))) __fp16 fp16x2;   // cvt_pkrtz return type
typedef __attribute__((ext_vector_type(2))) unsigned uint2v;

union H2U { half2v h; fp16x2 g; unsigned u; };
union H4U { half4v h4; half2v h2[2]; fp16x2 g2[2]; uint2v u2; };
union H8U { half8v h8; half2v h2[4]; fp16x2 g2[4]; };

__device__ __forceinline__ unsigned pkh(float a, float b) {
    H2U c; c.g = __builtin_amdgcn_cvt_pkrtz(a, b);
    return c.u;
}
__device__ __forceinline__ float fexp2(float x) {
#if __has_builtin(__builtin_amdgcn_exp2f)
    return __builtin_amdgcn_exp2f(x);
#else
    return exp2f(x);
#endif
}

struct Stage { float4 k0, k1, va, vb; };

__device__ __forceinline__ void stage_load(const float* __restrict__ Kg,
                                           const float* __restrict__ Vg,
                                           int kk, int dd, int kp, Stage& s) {
    s.k0 = *(const float4*)(Kg + (size_t)kk * D_ + dd);          // K rows 0..15
    s.k1 = *(const float4*)(Kg + (size_t)(kk + 16) * D_ + dd);   // K rows 16..31
    s.va = *(const float4*)(Vg + (size_t)(2 * kp) * D_ + dd);    // V row 2kp
    s.vb = *(const float4*)(Vg + (size_t)(2 * kp + 1) * D_ + dd);// V row 2kp+1
}

__device__ __forceinline__ void stage_store(unsigned* KsB, unsigned* VtB,
                                            int kwa, int kwb, const int* vw,
                                            const Stage& s) {
    *(uint2v*)&KsB[kwa] = (uint2v){ pkh(s.k0.x, s.k0.y), pkh(s.k0.z, s.k0.w) };
    *(uint2v*)&KsB[kwb] = (uint2v){ pkh(s.k1.x, s.k1.y), pkh(s.k1.z, s.k1.w) };
    // Vt dword = (V[2kp][d] low, V[2kp+1][d] high), XOR-swizzled pair column
    VtB[vw[0]] = pkh(s.va.x, s.vb.x);
    VtB[vw[1]] = pkh(s.va.y, s.vb.y);
    VtB[vw[2]] = pkh(s.va.z, s.vb.z);
    VtB[vw[3]] = pkh(s.va.w, s.vb.w);
}

__global__ __launch_bounds__(256, 4)
void attn_flash_st(const float* __restrict__ Q, const float* __restrict__ K,
                   const float* __restrict__ V, const int* __restrict__ mask,
                   float* __restrict__ out)
{
    __shared__ unsigned KsAll[2 * KS_SZ];
    __shared__ unsigned VtAll[2 * VT_SZ];

    const int tid  = threadIdx.x;
    const int lane = tid & 63;
    const int wave = tid >> 6;
    const int l15  = lane & 15;
    const int quad = lane >> 4;
    const int bh   = blockIdx.y;
    const int b    = bh / H_;
    const int qbase = blockIdx.x * 64 + wave * 16;
    const size_t qkv = (size_t)bh * S_ * D_;

    // ---- Q fragments (f16, scale folded), B-operand layout for K=32 mfma ----
    half8v qf[2];
    {
        const float* qrow = Q + qkv + (size_t)(qbase + l15) * D_ + quad * 8;
        #pragma unroll
        for (int dc = 0; dc < 2; ++dc) {
            float4 f0 = *(const float4*)(qrow + dc * 32);
            float4 f1 = *(const float4*)(qrow + dc * 32 + 4);
            H8U u;
            u.g2[0] = __builtin_amdgcn_cvt_pkrtz(f0.x * QSCALE, f0.y * QSCALE);
            u.g2[1] = __builtin_amdgcn_cvt_pkrtz(f0.z * QSCALE, f0.w * QSCALE);
            u.g2[2] = __builtin_amdgcn_cvt_pkrtz(f1.x * QSCALE, f1.y * QSCALE);
            u.g2[3] = __builtin_amdgcn_cvt_pkrtz(f1.z * QSCALE, f1.w * QSCALE);
            qf[dc] = u.h8;
        }
    }

    // ---- precomputed indices ----
    const int kk = tid >> 4;             // staging K row (and V pair index)
    const int dd = (tid & 15) * 4;       // staging d
    const int kwa = kk * KSD + (tid & 15) * 2;
    const int kwb = (kk + 16) * KSD + (tid & 15) * 2;
    int vw[4];
    #pragma unroll
    for (int m = 0; m < 4; ++m)
        vw[m] = (dd + m) * VTD + (kk ^ (((dd + m) & 7) << 1));

    // K frag read offsets (dwords): rows t*16+l15, d chunk dc*32 + quad*8
    int kroff[2][2];
    #pragma unroll
    for (int t = 0; t < 2; ++t)
        #pragma unroll
        for (int dc = 0; dc < 2; ++dc)
            kroff[t][dc] = (t * 16 + l15) * KSD + dc * 16 + quad * 4;
    // V frag read: row d = nb*16+l15, pair base (t*8 + quad*2) ^ swz(d)
    const int vswz = (l15 & 7) << 1;
    const int p0x[2] = { (quad * 2) ^ vswz, (8 + quad * 2) ^ vswz };
    int vrow[4];
    #pragma unroll
    for (int nb = 0; nb < 4; ++nb) vrow[nb] = (nb * 16 + l15) * VTD;

    // mask row pointer (per-lane q row, this quad's 4 columns)
    const int* mrow = mask + (size_t)b * S_ * S_ + (size_t)(qbase + l15) * S_ + quad * 4;

    // ---- state ----
    float m_run = -INFINITY, l_run = 0.0f;
    float4v o[4];
    #pragma unroll
    for (int nb = 0; nb < 4; ++nb) o[nb] = (float4v){0.f, 0.f, 0.f, 0.f};

    const float* Kg0 = K + qkv;
    const float* Vg0 = V + qkv;

    // ---- prologue: stage tile 0 into buffer 0 ----
    Stage cur;
    stage_load(Kg0, Vg0, kk, dd, kk, cur);
    stage_store(KsAll, VtAll, kwa, kwb, vw, cur);
    __syncthreads();

    for (int kt = 0; kt < NKT; ++kt) {
        const int buf = kt & 1;
        const unsigned* KsB = KsAll + buf * KS_SZ;
        const unsigned* VtB = VtAll + buf * VT_SZ;

        // prefetch next tile (global -> regs); clamped redundant load on last iter
        const int ktn = (kt + 1 < NKT) ? kt + 1 : NKT - 1;
        Stage nxt;
        stage_load(Kg0 + (size_t)ktn * BK * D_, Vg0 + (size_t)ktn * BK * D_, kk, dd, kk, nxt);

        // ---- S^T = K Q^T : two 16(k) x 16(q) C-tiles ----
        float4v st0 = (float4v){0.f,0.f,0.f,0.f}, st1 = st0;
        {
            half8v kf;
            kf = *(const half8v*)&KsB[kroff[0][0]];
            st0 = __builtin_amdgcn_mfma_f32_16x16x32_f16(kf, qf[0], st0, 0, 0, 0);
            kf = *(const half8v*)&KsB[kroff[0][1]];
            st0 = __builtin_amdgcn_mfma_f32_16x16x32_f16(kf, qf[1], st0, 0, 0, 0);
            kf = *(const half8v*)&KsB[kroff[1][0]];
            st1 = __builtin_amdgcn_mfma_f32_16x16x32_f16(kf, qf[0], st1, 0, 0, 0);
            kf = *(const half8v*)&KsB[kroff[1][1]];
            st1 = __builtin_amdgcn_mfma_f32_16x16x32_f16(kf, qf[1], st1, 0, 0, 0);
        }

        // ---- mask (C layout: col=q=l15, row=kcol=quad*4+r) ----
        const int4 mk0 = *(const int4*)(mrow);
        const int4 mk1 = *(const int4*)(mrow + 16);
        mrow += BK;
        st0.x = mk0.x ? -1e9f : st0.x;  st0.y = mk0.y ? -1e9f : st0.y;
        st0.z = mk0.z ? -1e9f : st0.z;  st0.w = mk0.w ? -1e9f : st0.w;
        st1.x = mk1.x ? -1e9f : st1.x;  st1.y = mk1.y ? -1e9f : st1.y;
        st1.z = mk1.z ? -1e9f : st1.z;  st1.w = mk1.w ? -1e9f : st1.w;

        // ---- online softmax (exp2 space; scale already folded into Q) ----
        float mx = fmaxf(fmaxf(fmaxf(st0.x, st0.y), fmaxf(st0.z, st0.w)),
                         fmaxf(fmaxf(st1.x, st1.y), fmaxf(st1.z, st1.w)));
        mx = fmaxf(mx, __shfl_xor(mx, 16, 64));
        mx = fmaxf(mx, __shfl_xor(mx, 32, 64));
        const float mnew = fmaxf(m_run, mx);
        const float alpha = fexp2(m_run - mnew);
        m_run = mnew;

        st0.x = fexp2(st0.x - mnew); st0.y = fexp2(st0.y - mnew);
        st0.z = fexp2(st0.z - mnew); st0.w = fexp2(st0.w - mnew);
        st1.x = fexp2(st1.x - mnew); st1.y = fexp2(st1.y - mnew);
        st1.z = fexp2(st1.z - mnew); st1.w = fexp2(st1.w - mnew);

        float ls = ((st0.x + st0.y) + (st0.z + st0.w)) +
                   ((st1.x + st1.y) + (st1.z + st1.w));
        ls += __shfl_xor(ls, 16, 64);
        ls += __shfl_xor(ls, 32, 64);
        l_run = l_run * alpha + ls;

        #pragma unroll
        for (int nb = 0; nb < 4; ++nb) o[nb] *= alpha;

        // ---- P fragments (f16): S^T C-layout == B-operand layout of 16x16x16 ----
        H4U pf0u, pf1u;
        pf0u.g2[0] = __builtin_amdgcn_cvt_pkrtz(st0.x, st0.y);
        pf0u.g2[1] = __builtin_amdgcn_cvt_pkrtz(st0.z, st0.w);
        pf1u.g2[0] = __builtin_amdgcn_cvt_pkrtz(st1.x, st1.y);
        pf1u.g2[1] = __builtin_amdgcn_cvt_pkrtz(st1.z, st1.w);

        // ---- O^T += V^T P : 4 d-tiles x 2 k-tiles of 16x16x16 ----
        #pragma unroll
        for (int nb = 0; nb < 4; ++nb) {
            H4U vf;
            vf.u2 = *(const uint2v*)&VtB[vrow[nb] + p0x[0]];
            o[nb] = __builtin_amdgcn_mfma_f32_16x16x16f16(vf.h4, pf0u.h4, o[nb], 0, 0, 0);
            vf.u2 = *(const uint2v*)&VtB[vrow[nb] + p0x[1]];
            o[nb] = __builtin_amdgcn_mfma_f32_16x16x16f16(vf.h4, pf1u.h4, o[nb], 0, 0, 0);
        }

        // ---- store prefetched tile into the other buffer ----
        stage_store((unsigned*)KsAll + (buf ^ 1) * KS_SZ,
                    (unsigned*)VtAll + (buf ^ 1) * VT_SZ, kwa, kwb, vw, nxt);
        __syncthreads();
    }

    // ---- epilogue: out[q][d] = O^T / l  (O^T: col=q=l15, row=d=quad*4+r) ----
    const float inv = 1.0f / l_run;
    float* orow = out + qkv + (size_t)(qbase + l15) * D_ + quad * 4;
    #pragma unroll
    for (int nb = 0; nb < 4; ++nb) {
        float4 ov = { o[nb].x * inv, o[nb].y * inv, o[nb].z * inv, o[nb].w * inv };
        *(float4*)(orow + nb * 16) = ov;
    }
}

extern "C" void kernel_launch(void* const* d_in, const int* in_sizes, int n_in,
                              void* d_out, int out_size, void* d_ws, size_t ws_size,
                              hipStream_t stream) {
    const float* Q    = (const float*)d_in[0];
    const float* K    = (const float*)d_in[1];
    const float* V    = (const float*)d_in[2];
    const int*   mask = (const int*)d_in[3];
    float* out = (float*)d_out;

    dim3 grid(S_ / 64, B_ * H_);   // 32 q-blocks x 32 (b,h)
    dim3 block(256);
    attn_flash_st<<<grid, block, 0, stream>>>(Q, K, V, mask, out);
}